// Round 2
// baseline (10867.484 us; speedup 1.0000x reference)
//
#include <hip/hip_runtime.h>
#include <hip/hip_bf16.h>
#include <cstdint>
#include <cstddef>

#define E_EDGES   640000
#define N_NODES_C 160000
#define N_GRAPHS  5000
#define HID       256
#define XDIM      128
#define EDIM      64

static constexpr size_t SZ_H  = (size_t)E_EDGES   * HID * sizeof(float); // 655,360,000
static constexpr size_t SZ_NS = (size_t)N_NODES_C * HID * sizeof(float); // 163,840,000
static constexpr size_t WS_NEED = 3 * SZ_H + SZ_NS;                      // ~2.13 GB

// Fallback workspace allocated at dlopen (outside graph capture), in case
// ws_size is smaller than we need. Branch on ws_size is deterministic.
static void* g_fb = nullptr;
__attribute__((constructor))
static void _fb_alloc() { (void)hipMalloc(&g_fb, WS_NEED); }

__device__ __forceinline__ float4 ldg4(const float* p) {
    return *reinterpret_cast<const float4*>(p);
}

// ---------------- GEMM: C[M x 256] = epilogue(A[M x K] @ W[K x 256]) -------
// BM=64 rows, BN=256 (full hidden width -> A gathered exactly once),
// BK=32, 256 threads. tx=tid&63 owns cols tx*4..+3, ty=tid>>6 owns rows
// ty*16..+15. A staged transposed As[k][m] (stride 68: 16B-aligned reads,
// wave-uniform broadcast since ty==wave id). B staged Bs[k][n] (contiguous
// 1KB/wave b128 reads).
// MODE 0: A = [x[src[e]], ea[e]]            -> out = relu(acc)          (h0)
// MODE 1: A = ns[src[e]] - hprev[rev[e]]    -> out = relu(h0 + acc)     (h)
// MODE 2: A = [x[n], ns[n]]                 -> atomicAdd(out[batch[n]], relu(acc+b3))
#define BM   64
#define BK   32
#define ASTR 68

template<int MODE, int KTOT>
__global__ __launch_bounds__(256)
void gemm_kernel(const float* __restrict__ x,
                 const float* __restrict__ ea,
                 const float* __restrict__ ns,
                 const float* __restrict__ hprev,
                 const float* __restrict__ h0,
                 const int*   __restrict__ src,
                 const int*   __restrict__ rev,
                 const int*   __restrict__ batch,
                 const float* __restrict__ W,
                 const float* __restrict__ b3,
                 float*       __restrict__ out)
{
    __shared__ __align__(16) float As[BK * ASTR];
    __shared__ __align__(16) float Bs[BK * 256];

    const int tid = threadIdx.x;
    const int tx  = tid & 63;
    const int ty  = tid >> 6;
    const int r0  = blockIdx.x * BM;

    float acc[16][4];
    #pragma unroll
    for (int i = 0; i < 16; ++i)
        #pragma unroll
        for (int j = 0; j < 4; ++j) acc[i][j] = 0.f;

    for (int kk = 0; kk < KTOT; kk += BK) {
        // ---- stage A tile: 64 rows x 32 k (512 float4 / 256 thr = 2 iters)
        #pragma unroll
        for (int it = 0; it < 2; ++it) {
            const int idx = tid + it * 256;
            const int row = idx >> 3;
            const int l4  = idx & 7;
            const int k   = kk + l4 * 4;
            const int gr  = r0 + row;
            float4 v;
            if (MODE == 0) {
                const int s = src[gr];
                v = (k < XDIM) ? ldg4(x  + (size_t)s  * XDIM + k)
                               : ldg4(ea + (size_t)gr * EDIM + (k - XDIM));
            } else if (MODE == 1) {
                const int s  = src[gr];
                const int rv = rev[gr];
                const float4 a = ldg4(ns    + (size_t)s  * HID + k);
                const float4 b = ldg4(hprev + (size_t)rv * HID + k);
                v = make_float4(a.x - b.x, a.y - b.y, a.z - b.z, a.w - b.w);
            } else {
                v = (k < XDIM) ? ldg4(x  + (size_t)gr * XDIM + k)
                               : ldg4(ns + (size_t)gr * HID + (k - XDIM));
            }
            As[(l4 * 4 + 0) * ASTR + row] = v.x;
            As[(l4 * 4 + 1) * ASTR + row] = v.y;
            As[(l4 * 4 + 2) * ASTR + row] = v.z;
            As[(l4 * 4 + 3) * ASTR + row] = v.w;
        }
        // ---- stage B tile: 32 rows x 256 cols (2048 float4 / 256 thr = 8)
        #pragma unroll
        for (int it = 0; it < 8; ++it) {
            const int idx  = tid + it * 256;
            const int brow = idx >> 6;
            const int bc4  = idx & 63;
            const float4 v = ldg4(W + (size_t)(kk + brow) * 256 + bc4 * 4);
            *reinterpret_cast<float4*>(&Bs[brow * 256 + bc4 * 4]) = v;
        }
        __syncthreads();

        // ---- micro-kernel
        #pragma unroll
        for (int k = 0; k < BK; ++k) {
            const float4 b = *reinterpret_cast<const float4*>(&Bs[k * 256 + tx * 4]);
            #pragma unroll
            for (int i = 0; i < 4; ++i) {
                const float4 a = *reinterpret_cast<const float4*>(&As[k * ASTR + ty * 16 + i * 4]);
                const float av[4] = {a.x, a.y, a.z, a.w};
                #pragma unroll
                for (int ii = 0; ii < 4; ++ii) {
                    acc[i * 4 + ii][0] += av[ii] * b.x;
                    acc[i * 4 + ii][1] += av[ii] * b.y;
                    acc[i * 4 + ii][2] += av[ii] * b.z;
                    acc[i * 4 + ii][3] += av[ii] * b.w;
                }
            }
        }
        __syncthreads();
    }

    // ---- epilogue
    const int c0 = tx * 4;
    #pragma unroll
    for (int i = 0; i < 4; ++i) {
        #pragma unroll
        for (int ii = 0; ii < 4; ++ii) {
            const int gr = r0 + ty * 16 + i * 4 + ii;
            float4 v = make_float4(acc[i * 4 + ii][0], acc[i * 4 + ii][1],
                                   acc[i * 4 + ii][2], acc[i * 4 + ii][3]);
            if (MODE == 0) {
                v.x = fmaxf(v.x, 0.f); v.y = fmaxf(v.y, 0.f);
                v.z = fmaxf(v.z, 0.f); v.w = fmaxf(v.w, 0.f);
                *reinterpret_cast<float4*>(out + (size_t)gr * HID + c0) = v;
            } else if (MODE == 1) {
                const float4 h0v = ldg4(h0 + (size_t)gr * HID + c0);
                v.x = fmaxf(v.x + h0v.x, 0.f); v.y = fmaxf(v.y + h0v.y, 0.f);
                v.z = fmaxf(v.z + h0v.z, 0.f); v.w = fmaxf(v.w + h0v.w, 0.f);
                *reinterpret_cast<float4*>(out + (size_t)gr * HID + c0) = v;
            } else {
                const float4 bb = ldg4(b3 + c0);
                v.x = fmaxf(v.x + bb.x, 0.f); v.y = fmaxf(v.y + bb.y, 0.f);
                v.z = fmaxf(v.z + bb.z, 0.f); v.w = fmaxf(v.w + bb.w, 0.f);
                const int g = batch[gr];
                float* p = out + (size_t)g * HID + c0;
                atomicAdd(p + 0, v.x);
                atomicAdd(p + 1, v.y);
                atomicAdd(p + 2, v.z);
                atomicAdd(p + 3, v.w);
            }
        }
    }
}

// ---------------- segment_sum(h, dst) via atomics ---------------------------
// One wave per edge: 64 lanes x float4 = the full 256-wide row. dst uniform
// per wave; avg degree E/N = 4 -> low contention.
__global__ __launch_bounds__(256)
void scatter_kernel(const float* __restrict__ h, const int* __restrict__ dst,
                    float* __restrict__ ns)
{
    const size_t gid = (size_t)blockIdx.x * 256 + threadIdx.x;
    const int e = (int)(gid >> 6);
    const int f = (int)(gid & 63) * 4;
    const float4 v = ldg4(h + (size_t)e * HID + f);
    const int d = dst[e];
    float* p = ns + (size_t)d * HID + f;
    atomicAdd(p + 0, v.x);
    atomicAdd(p + 1, v.y);
    atomicAdd(p + 2, v.z);
    atomicAdd(p + 3, v.w);
}

extern "C" void kernel_launch(void* const* d_in, const int* in_sizes, int n_in,
                              void* d_out, int out_size, void* d_ws, size_t ws_size,
                              hipStream_t stream)
{
    const float* x     = (const float*)d_in[0];
    const int*   eidx  = (const int*)  d_in[1];
    const int*   rev   = (const int*)  d_in[2];
    const float* ea    = (const float*)d_in[3];
    /* d_in[4] = num_nodes scalar, compile-time constant here */
    const int*   batch = (const int*)  d_in[5];
    const float* W1    = (const float*)d_in[6];
    const float* W2    = (const float*)d_in[7];
    const float* W3    = (const float*)d_in[8];
    const float* b3    = (const float*)d_in[9];
    float*       out   = (float*)d_out;

    const int* src = eidx;
    const int* dst = eidx + E_EDGES;

    char* base = (ws_size >= WS_NEED) ? (char*)d_ws : (char*)g_fb;
    float* h0 = (float*)(base);
    float* hB = (float*)(base + SZ_H);
    float* hC = (float*)(base + 2 * SZ_H);
    float* ns = (float*)(base + 3 * SZ_H);

    const dim3 blk(256);
    const int gE = E_EDGES / BM;      // 10000
    const int gN = N_NODES_C / BM;    // 2500
    const int gS = E_EDGES / 4;       // 160000 (E*64 threads / 256)

    // h0 = relu([x[src], ea] @ W1)
    gemm_kernel<0, 192><<<gE, blk, 0, stream>>>(x, ea, nullptr, nullptr, nullptr,
                                                src, nullptr, nullptr, W1, nullptr, h0);
    // iter 1: ns = segsum(h0, dst); hB = relu(h0 + (ns[src]-h0[rev]) @ W2)
    hipMemsetAsync(ns, 0, SZ_NS, stream);
    scatter_kernel<<<gS, blk, 0, stream>>>(h0, dst, ns);
    gemm_kernel<1, 256><<<gE, blk, 0, stream>>>(nullptr, nullptr, ns, h0, h0,
                                                src, rev, nullptr, W2, nullptr, hB);
    // iter 2
    hipMemsetAsync(ns, 0, SZ_NS, stream);
    scatter_kernel<<<gS, blk, 0, stream>>>(hB, dst, ns);
    gemm_kernel<1, 256><<<gE, blk, 0, stream>>>(nullptr, nullptr, ns, hB, h0,
                                                src, rev, nullptr, W2, nullptr, hC);
    // v_msg = segsum(hC, dst)
    hipMemsetAsync(ns, 0, SZ_NS, stream);
    scatter_kernel<<<gS, blk, 0, stream>>>(hC, dst, ns);
    // out[g] += relu([x, ns] @ W3 + b3)
    hipMemsetAsync(out, 0, (size_t)out_size * sizeof(float), stream);
    gemm_kernel<2, 384><<<gN, blk, 0, stream>>>(x, nullptr, ns, nullptr, nullptr,
                                                nullptr, nullptr, batch, W3, b3, out);
}

// Round 4
// 4998.989 us; speedup vs baseline: 2.1739x; 2.1739x over previous
//
#include <hip/hip_runtime.h>
#include <hip/hip_bf16.h>
#include <cstdint>
#include <cstddef>

#define E_EDGES   640000
#define N_NODES_C 160000
#define N_GRAPHS  5000
#define HID       256
#define XDIM      128
#define EDIM      64
#define SCAN_B    625            // N_NODES_C / 256

static constexpr size_t SZ_H  = (size_t)E_EDGES   * HID * sizeof(float); // 655,360,000
static constexpr size_t SZ_NS = (size_t)N_NODES_C * HID * sizeof(float); // 163,840,000
static constexpr size_t SZ_CSR = (size_t)(2 * N_NODES_C + 1 + E_EDGES + 1024) * sizeof(int);
static constexpr size_t WS_NEED = 3 * SZ_H + SZ_NS + SZ_CSR;

// Fallback workspace allocated at dlopen (outside graph capture), in case
// ws_size is smaller than we need. Branch on ws_size is deterministic.
static void* g_fb = nullptr;
__attribute__((constructor))
static void _fb_alloc() { (void)hipMalloc(&g_fb, WS_NEED); }

__device__ __forceinline__ float4 ldg4(const float* p) {
    return *reinterpret_cast<const float4*>(p);
}

// ---------------- GEMM: C[M x 256] = epilogue(A[M x K] @ W[K x 256]) -------
// BM=64 rows, BN=256 (full hidden width -> A gathered exactly once),
// BK=32, 256 threads. tx owns cols tx*4..+3, ty=tid>>6 owns rows ty*16..+15.
// MODE 0: A = [x[src[e]], ea[e]]            -> out = relu(acc)          (h0)
// MODE 1: A = ns[src[e]] - hprev[rev[e]]    -> out = relu(h0 + acc)     (h)
// MODE 2: A = [x[n], ns[n]]                 -> atomicAdd(out[batch[n]], relu(acc+b3))
#define BM   64
#define BK   32
#define ASTR 68

template<int MODE, int KTOT>
__global__ __launch_bounds__(256)
void gemm_kernel(const float* __restrict__ x,
                 const float* __restrict__ ea,
                 const float* __restrict__ ns,
                 const float* __restrict__ hprev,
                 const float* __restrict__ h0,
                 const int*   __restrict__ src,
                 const int*   __restrict__ rev,
                 const int*   __restrict__ batch,
                 const float* __restrict__ W,
                 const float* __restrict__ b3,
                 float*       __restrict__ out)
{
    __shared__ __align__(16) float As[BK * ASTR];
    __shared__ __align__(16) float Bs[BK * 256];

    const int tid = threadIdx.x;
    const int tx  = tid & 63;
    const int ty  = tid >> 6;
    const int r0  = blockIdx.x * BM;

    float acc[16][4];
    #pragma unroll
    for (int i = 0; i < 16; ++i)
        #pragma unroll
        for (int j = 0; j < 4; ++j) acc[i][j] = 0.f;

    for (int kk = 0; kk < KTOT; kk += BK) {
        #pragma unroll
        for (int it = 0; it < 2; ++it) {
            const int idx = tid + it * 256;
            const int row = idx >> 3;
            const int l4  = idx & 7;
            const int k   = kk + l4 * 4;
            const int gr  = r0 + row;
            float4 v;
            if (MODE == 0) {
                const int s = src[gr];
                v = (k < XDIM) ? ldg4(x  + (size_t)s  * XDIM + k)
                               : ldg4(ea + (size_t)gr * EDIM + (k - XDIM));
            } else if (MODE == 1) {
                const int s  = src[gr];
                const int rv = rev[gr];
                const float4 a = ldg4(ns    + (size_t)s  * HID + k);
                const float4 b = ldg4(hprev + (size_t)rv * HID + k);
                v = make_float4(a.x - b.x, a.y - b.y, a.z - b.z, a.w - b.w);
            } else {
                v = (k < XDIM) ? ldg4(x  + (size_t)gr * XDIM + k)
                               : ldg4(ns + (size_t)gr * HID + (k - XDIM));
            }
            As[(l4 * 4 + 0) * ASTR + row] = v.x;
            As[(l4 * 4 + 1) * ASTR + row] = v.y;
            As[(l4 * 4 + 2) * ASTR + row] = v.z;
            As[(l4 * 4 + 3) * ASTR + row] = v.w;
        }
        #pragma unroll
        for (int it = 0; it < 8; ++it) {
            const int idx  = tid + it * 256;
            const int brow = idx >> 6;
            const int bc4  = idx & 63;
            const float4 v = ldg4(W + (size_t)(kk + brow) * 256 + bc4 * 4);
            *reinterpret_cast<float4*>(&Bs[brow * 256 + bc4 * 4]) = v;
        }
        __syncthreads();

        #pragma unroll
        for (int k = 0; k < BK; ++k) {
            const float4 b = *reinterpret_cast<const float4*>(&Bs[k * 256 + tx * 4]);
            #pragma unroll
            for (int i = 0; i < 4; ++i) {
                const float4 a = *reinterpret_cast<const float4*>(&As[k * ASTR + ty * 16 + i * 4]);
                const float av[4] = {a.x, a.y, a.z, a.w};
                #pragma unroll
                for (int ii = 0; ii < 4; ++ii) {
                    acc[i * 4 + ii][0] += av[ii] * b.x;
                    acc[i * 4 + ii][1] += av[ii] * b.y;
                    acc[i * 4 + ii][2] += av[ii] * b.z;
                    acc[i * 4 + ii][3] += av[ii] * b.w;
                }
            }
        }
        __syncthreads();
    }

    const int c0 = tx * 4;
    #pragma unroll
    for (int i = 0; i < 4; ++i) {
        #pragma unroll
        for (int ii = 0; ii < 4; ++ii) {
            const int gr = r0 + ty * 16 + i * 4 + ii;
            float4 v = make_float4(acc[i * 4 + ii][0], acc[i * 4 + ii][1],
                                   acc[i * 4 + ii][2], acc[i * 4 + ii][3]);
            if (MODE == 0) {
                v.x = fmaxf(v.x, 0.f); v.y = fmaxf(v.y, 0.f);
                v.z = fmaxf(v.z, 0.f); v.w = fmaxf(v.w, 0.f);
                *reinterpret_cast<float4*>(out + (size_t)gr * HID + c0) = v;
            } else if (MODE == 1) {
                const float4 h0v = ldg4(h0 + (size_t)gr * HID + c0);
                v.x = fmaxf(v.x + h0v.x, 0.f); v.y = fmaxf(v.y + h0v.y, 0.f);
                v.z = fmaxf(v.z + h0v.z, 0.f); v.w = fmaxf(v.w + h0v.w, 0.f);
                *reinterpret_cast<float4*>(out + (size_t)gr * HID + c0) = v;
            } else {
                const float4 bb = ldg4(b3 + c0);
                v.x = fmaxf(v.x + bb.x, 0.f); v.y = fmaxf(v.y + bb.y, 0.f);
                v.z = fmaxf(v.z + bb.z, 0.f); v.w = fmaxf(v.w + bb.w, 0.f);
                const int g = batch[gr];
                float* p = out + (size_t)g * HID + c0;
                atomicAdd(p + 0, v.x);
                atomicAdd(p + 1, v.y);
                atomicAdd(p + 2, v.z);
                atomicAdd(p + 3, v.w);
            }
        }
    }
}

// ---------------- CSR build (per launch; dst is fixed) ----------------------
__global__ __launch_bounds__(256)
void hist_kernel(const int* __restrict__ dst, int* __restrict__ deg)
{
    const int e = blockIdx.x * 256 + threadIdx.x;
    atomicAdd(&deg[dst[e]], 1);
}

__global__ __launch_bounds__(256)
void scan1_kernel(int* __restrict__ off, int* __restrict__ part)
{
    __shared__ int buf[256];
    const int t = threadIdx.x;
    const int i = blockIdx.x * 256 + t;
    const int v = off[i];
    buf[t] = v; __syncthreads();
    #pragma unroll
    for (int o = 1; o < 256; o <<= 1) {
        const int val = (t >= o) ? buf[t - o] : 0;
        __syncthreads();
        buf[t] += val;
        __syncthreads();
    }
    off[i] = buf[t] - v;                 // exclusive within block
    if (t == 255) part[blockIdx.x] = buf[t];
}

__global__ __launch_bounds__(1024)
void scan2_kernel(int* __restrict__ part)
{
    __shared__ int buf[1024];
    const int t = threadIdx.x;
    const int v = (t < SCAN_B) ? part[t] : 0;
    buf[t] = v; __syncthreads();
    #pragma unroll
    for (int o = 1; o < 1024; o <<= 1) {
        const int val = (t >= o) ? buf[t - o] : 0;
        __syncthreads();
        buf[t] += val;
        __syncthreads();
    }
    if (t < SCAN_B) part[t] = buf[t] - v; // exclusive block offsets
}

__global__ __launch_bounds__(256)
void scan3_kernel(int* __restrict__ off, const int* __restrict__ part,
                  int* __restrict__ pos)
{
    const int i = blockIdx.x * 256 + threadIdx.x;
    const int v = off[i] + part[blockIdx.x];
    off[i] = v;
    pos[i] = v;
    if (i == 0) off[N_NODES_C] = E_EDGES;
}

__global__ __launch_bounds__(256)
void fill_kernel(const int* __restrict__ dst, int* __restrict__ pos,
                 int* __restrict__ elist)
{
    const int e = blockIdx.x * 256 + threadIdx.x;
    const int idx = atomicAdd(&pos[dst[e]], 1);
    elist[idx] = e;
}

// ---------------- segment_sum(h, dst) via CSR gather ------------------------
// One wave per node: 64 lanes x float4 = full 256-wide row. Loop over the
// node's incoming edges, accumulate in registers, single write. No atomics.
__global__ __launch_bounds__(256)
void gather_kernel(const float* __restrict__ h, const int* __restrict__ off,
                   const int* __restrict__ elist, float* __restrict__ ns)
{
    const size_t gid = (size_t)blockIdx.x * 256 + threadIdx.x;
    const int n    = (int)(gid >> 6);
    const int lane = (int)(gid & 63);
    const int s  = off[n];
    const int en = off[n + 1];
    float4 acc = make_float4(0.f, 0.f, 0.f, 0.f);
    for (int p = s; p < en; ++p) {
        const int e = elist[p];
        const float4 v = ldg4(h + (size_t)e * HID + lane * 4);
        acc.x += v.x; acc.y += v.y; acc.z += v.z; acc.w += v.w;
    }
    *reinterpret_cast<float4*>(ns + (size_t)n * HID + lane * 4) = acc;
}

extern "C" void kernel_launch(void* const* d_in, const int* in_sizes, int n_in,
                              void* d_out, int out_size, void* d_ws, size_t ws_size,
                              hipStream_t stream)
{
    const float* x     = (const float*)d_in[0];
    const int*   eidx  = (const int*)  d_in[1];
    const int*   rev   = (const int*)  d_in[2];
    const float* ea    = (const float*)d_in[3];
    const int*   batch = (const int*)  d_in[5];
    const float* W1    = (const float*)d_in[6];
    const float* W2    = (const float*)d_in[7];
    const float* W3    = (const float*)d_in[8];
    const float* b3    = (const float*)d_in[9];
    float*       out   = (float*)d_out;

    const int* src = eidx;
    const int* dst = eidx + E_EDGES;

    char* base = (ws_size >= WS_NEED) ? (char*)d_ws : (char*)g_fb;
    float* h0 = (float*)(base);
    float* hB = (float*)(base + SZ_H);
    float* hC = (float*)(base + 2 * SZ_H);
    float* ns = (float*)(base + 3 * SZ_H);
    int*   off   = (int*)(base + 3 * SZ_H + SZ_NS);
    int*   pos   = off + (N_NODES_C + 1);
    int*   elist = pos + N_NODES_C;
    int*   part  = elist + E_EDGES;

    const dim3 blk(256);
    const int gE  = E_EDGES / BM;     // 10000
    const int gN  = N_NODES_C / BM;   // 2500
    const int gEt = E_EDGES / 256;    // 2500
    const int gNg = N_NODES_C / 4;    // 40000 blocks: 1 wave per node

    // ---- build CSR over dst (once; reused by all 3 segment-sums)
    hipMemsetAsync(off, 0, (N_NODES_C + 1) * sizeof(int), stream);
    hist_kernel <<<gEt,    blk, 0, stream>>>(dst, off);
    scan1_kernel<<<SCAN_B, blk, 0, stream>>>(off, part);
    scan2_kernel<<<1,     1024, 0, stream>>>(part);
    scan3_kernel<<<SCAN_B, blk, 0, stream>>>(off, part, pos);
    fill_kernel <<<gEt,    blk, 0, stream>>>(dst, pos, elist);

    // h0 = relu([x[src], ea] @ W1)
    gemm_kernel<0, 192><<<gE, blk, 0, stream>>>(x, ea, nullptr, nullptr, nullptr,
                                                src, nullptr, nullptr, W1, nullptr, h0);
    // iter 1
    gather_kernel<<<gNg, blk, 0, stream>>>(h0, off, elist, ns);
    gemm_kernel<1, 256><<<gE, blk, 0, stream>>>(nullptr, nullptr, ns, h0, h0,
                                                src, rev, nullptr, W2, nullptr, hB);
    // iter 2
    gather_kernel<<<gNg, blk, 0, stream>>>(hB, off, elist, ns);
    gemm_kernel<1, 256><<<gE, blk, 0, stream>>>(nullptr, nullptr, ns, hB, h0,
                                                src, rev, nullptr, W2, nullptr, hC);
    // v_msg = segsum(hC, dst)
    gather_kernel<<<gNg, blk, 0, stream>>>(hC, off, elist, ns);
    // out[g] += relu([x, ns] @ W3 + b3)
    hipMemsetAsync(out, 0, (size_t)out_size * sizeof(float), stream);
    gemm_kernel<2, 384><<<gN, blk, 0, stream>>>(x, nullptr, ns, nullptr, nullptr,
                                                nullptr, nullptr, batch, W3, b3, out);
}

// Round 5
// 4253.846 us; speedup vs baseline: 2.5547x; 1.1752x over previous
//
#include <hip/hip_runtime.h>
#include <hip/hip_bf16.h>
#include <cstdint>
#include <cstddef>

#define E_EDGES   640000
#define N_NODES_C 160000
#define N_GRAPHS  5000
#define HID       256
#define XDIM      128
#define EDIM      64
#define SCAN_B    625            // N_NODES_C / 256

typedef unsigned short u16;
typedef __attribute__((ext_vector_type(8))) short short8;  // 8 bf16 = 4 VGPR
typedef __attribute__((ext_vector_type(4))) float f32x4;   // MFMA C/D

static constexpr size_t SZ_HB  = (size_t)E_EDGES * HID * 2;       // 327,680,000
static constexpr size_t SZ_NSB = (size_t)N_NODES_C * HID * 2;     // 81,920,000
static constexpr size_t SZ_WT  = (size_t)((192 + 256 + 384) / 8) * HID * 8 * 2; // 425,984
static constexpr size_t SZ_CSR = (size_t)(2 * N_NODES_C + 1 + E_EDGES + 1024) * 4;
static constexpr size_t WS_NEED = 3 * SZ_HB + SZ_NSB + SZ_WT + SZ_CSR; // ~1.07 GB

// Fallback workspace allocated at dlopen (outside graph capture).
static void* g_fb = nullptr;
__attribute__((constructor))
static void _fb_alloc() { (void)hipMalloc(&g_fb, WS_NEED); }

__device__ __forceinline__ float bf2f(u16 u) {
    return __uint_as_float(((unsigned)u) << 16);
}
__device__ __forceinline__ u16 f2bf(float f) {   // round-to-nearest-even
    unsigned b = __float_as_uint(f);
    return (u16)((b + 0x7FFFu + ((b >> 16) & 1u)) >> 16);
}
__device__ __forceinline__ short8 ld8f(const float* p) {  // 8 fp32 -> 8 bf16
    const float4 v0 = *reinterpret_cast<const float4*>(p);
    const float4 v1 = *reinterpret_cast<const float4*>(p + 4);
    short8 r;
    r[0] = (short)f2bf(v0.x); r[1] = (short)f2bf(v0.y);
    r[2] = (short)f2bf(v0.z); r[3] = (short)f2bf(v0.w);
    r[4] = (short)f2bf(v1.x); r[5] = (short)f2bf(v1.y);
    r[6] = (short)f2bf(v1.z); r[7] = (short)f2bf(v1.w);
    return r;
}

// ---------------- W -> fragment-major bf16: Wt[(kb*256+c)*8+i] = W[kb*8+i][c]
__global__ __launch_bounds__(256)
void wt_kernel(const float* __restrict__ W, u16* __restrict__ Wt)
{
    const int id = blockIdx.x * 256 + threadIdx.x;
    const int kb = id >> 8, c = id & 255;
    #pragma unroll
    for (int i = 0; i < 8; ++i)
        Wt[((size_t)kb * 256 + c) * 8 + i] = f2bf(W[(size_t)(kb * 8 + i) * 256 + c]);
}

// ---------------- MFMA GEMM: C[M x 256] = epilogue(A[M x K] @ W[K x 256]) ---
// 256 thr = 4 waves. Block: 64 rows x 256 cols. Wave w: 64 rows x cols
// [w*64, w*64+64). No LDS, no barriers. Operand-swapped 16x16x32 bf16 MFMA:
// A-slot = W-frag (col-major tile), B-slot = our-rows frag -> per lane all 64
// outputs in ONE row (row = r0+g*16+(l&15), cols w*64+t*16+q*4+v).
// MODE 0: A = [x[src[e]] | ea[e]] fp32      -> h0 = relu(acc)         K=192
// MODE 1: A = ns[src[e]] - hp[rev[e]] bf16  -> h = relu(h0 + acc)     K=256
// MODE 2: A = [x[n] | ns[n]]                -> out[batch]+=relu(acc+b3) K=384
template<int MODE, int KTOT>
__global__ __launch_bounds__(256, 3)
void mfma_gemm(const float* __restrict__ x,
               const float* __restrict__ ea,
               const u16*   __restrict__ ns,
               const u16*   __restrict__ hp,
               const u16*   __restrict__ h0,
               const int*   __restrict__ src,
               const int*   __restrict__ rev,
               const int*   __restrict__ batch,
               const u16*   __restrict__ Wt,
               const float* __restrict__ b3,
               void*        __restrict__ outv)
{
    const int tid = threadIdx.x;
    const int l   = tid & 63;
    const int w   = tid >> 6;
    const int q   = l >> 4;      // k-quarter: k = kk + q*8 + i
    const int rl  = l & 15;
    const int r0  = blockIdx.x * 64;

    // B (weight) fragment base: element (kb=kk/8+q, c=w*64+t*16+rl)
    const u16* Wb = Wt + ((size_t)q * 256 + w * 64 + rl) * 8;

    int rows[4];
    const u16*   ap[4] = {nullptr, nullptr, nullptr, nullptr};
    const u16*   bp[4] = {nullptr, nullptr, nullptr, nullptr};
    const float* fp[4] = {nullptr, nullptr, nullptr, nullptr};
    const float* gp[4] = {nullptr, nullptr, nullptr, nullptr};
    #pragma unroll
    for (int g = 0; g < 4; ++g) {
        const int r = r0 + g * 16 + rl;
        rows[g] = r;
        if (MODE == 0) {
            fp[g] = x  + (size_t)src[r] * XDIM + q * 8;   // gathered x
            gp[g] = ea + (size_t)r * EDIM + q * 8;        // streamed ea
        } else if (MODE == 1) {
            ap[g] = ns + (size_t)src[r] * HID + q * 8;    // gathered ns
            bp[g] = hp + (size_t)rev[r] * HID + q * 8;    // gathered h_prev
        } else {
            fp[g] = x  + (size_t)r * XDIM + q * 8;        // streamed x
            ap[g] = ns + (size_t)r * HID + q * 8;         // streamed ns
        }
    }

    f32x4 acc[4][4];
    #pragma unroll
    for (int g = 0; g < 4; ++g)
        #pragma unroll
        for (int t = 0; t < 4; ++t)
            acc[g][t] = (f32x4){0.f, 0.f, 0.f, 0.f};

    for (int kk = 0; kk < KTOT; kk += 32) {
        short8 bfr[4];
        #pragma unroll
        for (int t = 0; t < 4; ++t)   // (kk/8)*2048 == kk*256 (u16 elements)
            bfr[t] = *reinterpret_cast<const short8*>(Wb + (size_t)kk * 256 + t * 128);

        short8 afr[4];
        #pragma unroll
        for (int g = 0; g < 4; ++g) {
            if (MODE == 1) {
                const short8 a = *reinterpret_cast<const short8*>(ap[g] + kk);
                const short8 b = *reinterpret_cast<const short8*>(bp[g] + kk);
                #pragma unroll
                for (int i = 0; i < 8; ++i)
                    afr[g][i] = (short)f2bf(bf2f((u16)a[i]) - bf2f((u16)b[i]));
            } else if (MODE == 0) {
                afr[g] = (kk < XDIM) ? ld8f(fp[g] + kk) : ld8f(gp[g] + (kk - XDIM));
            } else {
                if (kk < XDIM) {
                    afr[g] = ld8f(fp[g] + kk);
                } else {
                    afr[g] = *reinterpret_cast<const short8*>(ap[g] + (kk - XDIM));
                }
            }
        }

        #pragma unroll
        for (int g = 0; g < 4; ++g)
            #pragma unroll
            for (int t = 0; t < 4; ++t)
                acc[g][t] = __builtin_amdgcn_mfma_f32_16x16x32_bf16(
                                bfr[t], afr[g], acc[g][t], 0, 0, 0);
    }

    // Epilogue: lane l holds C[rows[g]][w*64 + t*16 + q*4 + v]
    #pragma unroll
    for (int g = 0; g < 4; ++g) {
        const int row = rows[g];
        if (MODE == 2) {
            const int gb = batch[row];
            float* op = (float*)outv + (size_t)gb * HID;
            #pragma unroll
            for (int t = 0; t < 4; ++t) {
                const int c0 = w * 64 + t * 16 + q * 4;
                #pragma unroll
                for (int v = 0; v < 4; ++v) {
                    const float r = fmaxf(acc[g][t][v] + b3[c0 + v], 0.f);
                    atomicAdd(op + c0 + v, r);
                }
            }
        } else {
            u16* op = (u16*)outv + (size_t)row * HID;
            #pragma unroll
            for (int t = 0; t < 4; ++t) {
                const int c0 = w * 64 + t * 16 + q * 4;
                float e0 = acc[g][t][0], e1 = acc[g][t][1];
                float e2 = acc[g][t][2], e3 = acc[g][t][3];
                if (MODE == 1) {
                    const ushort4 hv = *reinterpret_cast<const ushort4*>(
                        h0 + (size_t)row * HID + c0);
                    e0 += bf2f(hv.x); e1 += bf2f(hv.y);
                    e2 += bf2f(hv.z); e3 += bf2f(hv.w);
                }
                ushort4 o;
                o.x = f2bf(fmaxf(e0, 0.f)); o.y = f2bf(fmaxf(e1, 0.f));
                o.z = f2bf(fmaxf(e2, 0.f)); o.w = f2bf(fmaxf(e3, 0.f));
                *reinterpret_cast<ushort4*>(op + c0) = o;
            }
        }
    }
}

// ---------------- CSR build (dst fixed per launch) --------------------------
__global__ __launch_bounds__(256)
void hist_kernel(const int* __restrict__ dst, int* __restrict__ deg)
{
    const int e = blockIdx.x * 256 + threadIdx.x;
    atomicAdd(&deg[dst[e]], 1);
}

__global__ __launch_bounds__(256)
void scan1_kernel(int* __restrict__ off, int* __restrict__ part)
{
    __shared__ int buf[256];
    const int t = threadIdx.x;
    const int i = blockIdx.x * 256 + t;
    const int v = off[i];
    buf[t] = v; __syncthreads();
    #pragma unroll
    for (int o = 1; o < 256; o <<= 1) {
        const int val = (t >= o) ? buf[t - o] : 0;
        __syncthreads();
        buf[t] += val;
        __syncthreads();
    }
    off[i] = buf[t] - v;
    if (t == 255) part[blockIdx.x] = buf[t];
}

__global__ __launch_bounds__(1024)
void scan2_kernel(int* __restrict__ part)
{
    __shared__ int buf[1024];
    const int t = threadIdx.x;
    const int v = (t < SCAN_B) ? part[t] : 0;
    buf[t] = v; __syncthreads();
    #pragma unroll
    for (int o = 1; o < 1024; o <<= 1) {
        const int val = (t >= o) ? buf[t - o] : 0;
        __syncthreads();
        buf[t] += val;
        __syncthreads();
    }
    if (t < SCAN_B) part[t] = buf[t] - v;
}

__global__ __launch_bounds__(256)
void scan3_kernel(int* __restrict__ off, const int* __restrict__ part,
                  int* __restrict__ pos)
{
    const int i = blockIdx.x * 256 + threadIdx.x;
    const int v = off[i] + part[blockIdx.x];
    off[i] = v;
    pos[i] = v;
    if (i == 0) off[N_NODES_C] = E_EDGES;
}

__global__ __launch_bounds__(256)
void fill_kernel(const int* __restrict__ dst, int* __restrict__ pos,
                 int* __restrict__ elist)
{
    const int e = blockIdx.x * 256 + threadIdx.x;
    const int idx = atomicAdd(&pos[dst[e]], 1);
    elist[idx] = e;
}

// ---------------- segment_sum via CSR gather (bf16) -------------------------
// One wave per node: 64 lanes x 4 bf16 = 256-wide row. fp32 accumulate.
__global__ __launch_bounds__(256)
void gather_bf(const u16* __restrict__ h, const int* __restrict__ off,
               const int* __restrict__ elist, u16* __restrict__ ns)
{
    const size_t gid = (size_t)blockIdx.x * 256 + threadIdx.x;
    const int n = (int)(gid >> 6);
    const int c = (int)(gid & 63) * 4;
    const int s = off[n], e1 = off[n + 1];
    float a0 = 0.f, a1 = 0.f, a2 = 0.f, a3 = 0.f;
    for (int p = s; p < e1; ++p) {
        const int e = elist[p];
        const ushort4 v = *reinterpret_cast<const ushort4*>(h + (size_t)e * HID + c);
        a0 += bf2f(v.x); a1 += bf2f(v.y); a2 += bf2f(v.z); a3 += bf2f(v.w);
    }
    ushort4 o;
    o.x = f2bf(a0); o.y = f2bf(a1); o.z = f2bf(a2); o.w = f2bf(a3);
    *reinterpret_cast<ushort4*>(ns + (size_t)n * HID + c) = o;
}

extern "C" void kernel_launch(void* const* d_in, const int* in_sizes, int n_in,
                              void* d_out, int out_size, void* d_ws, size_t ws_size,
                              hipStream_t stream)
{
    const float* x     = (const float*)d_in[0];
    const int*   eidx  = (const int*)  d_in[1];
    const int*   rev   = (const int*)  d_in[2];
    const float* ea    = (const float*)d_in[3];
    const int*   batch = (const int*)  d_in[5];
    const float* W1    = (const float*)d_in[6];
    const float* W2    = (const float*)d_in[7];
    const float* W3    = (const float*)d_in[8];
    const float* b3    = (const float*)d_in[9];
    float*       out   = (float*)d_out;

    const int* src = eidx;
    const int* dst = eidx + E_EDGES;

    char* base = (ws_size >= WS_NEED) ? (char*)d_ws : (char*)g_fb;
    u16* h0  = (u16*)(base);
    u16* hB  = (u16*)(base + SZ_HB);
    u16* hC  = (u16*)(base + 2 * SZ_HB);
    u16* ns  = (u16*)(base + 3 * SZ_HB);
    u16* wt1 = (u16*)(base + 3 * SZ_HB + SZ_NSB);
    u16* wt2 = wt1 + (size_t)24 * 256 * 8;   // K=192 -> 24 kb
    u16* wt3 = wt2 + (size_t)32 * 256 * 8;   // K=256 -> 32 kb
    int* off   = (int*)(base + 3 * SZ_HB + SZ_NSB + SZ_WT);
    int* pos   = off + (N_NODES_C + 1);
    int* elist = pos + N_NODES_C;
    int* part  = elist + E_EDGES;

    const dim3 blk(256);
    const int gE  = E_EDGES / 64;     // 10000
    const int gN  = N_NODES_C / 64;   // 2500
    const int gEt = E_EDGES / 256;    // 2500
    const int gNg = N_NODES_C / 4;    // 40000: 1 wave per node

    // weights -> fragment-major bf16
    wt_kernel<<<24, blk, 0, stream>>>(W1, wt1);
    wt_kernel<<<32, blk, 0, stream>>>(W2, wt2);
    wt_kernel<<<48, blk, 0, stream>>>(W3, wt3);

    // CSR over dst (reused by all 3 segment-sums)
    hipMemsetAsync(off, 0, (N_NODES_C + 1) * sizeof(int), stream);
    hist_kernel <<<gEt,    blk, 0, stream>>>(dst, off);
    scan1_kernel<<<SCAN_B, blk, 0, stream>>>(off, part);
    scan2_kernel<<<1,     1024, 0, stream>>>(part);
    scan3_kernel<<<SCAN_B, blk, 0, stream>>>(off, part, pos);
    fill_kernel <<<gEt,    blk, 0, stream>>>(dst, pos, elist);

    // h0 = relu([x[src]|ea] @ W1)
    mfma_gemm<0, 192><<<gE, blk, 0, stream>>>(x, ea, nullptr, nullptr, nullptr,
                                              src, nullptr, nullptr, wt1, nullptr, h0);
    // iter 1
    gather_bf<<<gNg, blk, 0, stream>>>(h0, off, elist, ns);
    mfma_gemm<1, 256><<<gE, blk, 0, stream>>>(nullptr, nullptr, ns, h0, h0,
                                              src, rev, nullptr, wt2, nullptr, hB);
    // iter 2
    gather_bf<<<gNg, blk, 0, stream>>>(hB, off, elist, ns);
    mfma_gemm<1, 256><<<gE, blk, 0, stream>>>(nullptr, nullptr, ns, hB, h0,
                                              src, rev, nullptr, wt2, nullptr, hC);
    // v_msg
    gather_bf<<<gNg, blk, 0, stream>>>(hC, off, elist, ns);
    // out[g] += relu([x|ns] @ W3 + b3)
    hipMemsetAsync(out, 0, (size_t)out_size * sizeof(float), stream);
    mfma_gemm<2, 384><<<gN, blk, 0, stream>>>(x, nullptr, ns, nullptr, nullptr,
                                              nullptr, nullptr, batch, wt3, b3, out);
}

// Round 6
// 3641.519 us; speedup vs baseline: 2.9843x; 1.1682x over previous
//
#include <hip/hip_runtime.h>
#include <hip/hip_bf16.h>
#include <cstdint>
#include <cstddef>

#define E_EDGES   640000
#define N_NODES_C 160000
#define N_GRAPHS  5000
#define HID       256
#define XDIM      128
#define EDIM      64
#define SCAN_B    625            // N_NODES_C / 256

typedef unsigned short u16;
typedef __attribute__((ext_vector_type(8))) short short8;  // 8 bf16 = 4 VGPR
typedef __attribute__((ext_vector_type(4))) float f32x4;   // MFMA C/D

static constexpr size_t SZ_HB  = (size_t)E_EDGES * HID * 2;       // 327,680,000
static constexpr size_t SZ_NSB = (size_t)N_NODES_C * HID * 2;     // 81,920,000
static constexpr size_t SZ_WT  = (size_t)((192 + 256 + 384) / 8) * HID * 8 * 2;
static constexpr size_t SZ_CSR = (size_t)(2 * N_NODES_C + 1 + E_EDGES + 1024) * 4;
static constexpr size_t WS_NEED = 3 * SZ_HB + SZ_NSB + SZ_WT + SZ_CSR; // ~1.07 GB

static void* g_fb = nullptr;
__attribute__((constructor))
static void _fb_alloc() { (void)hipMalloc(&g_fb, WS_NEED); }

__device__ __forceinline__ float bf2f(u16 u) {
    return __uint_as_float(((unsigned)u) << 16);
}
__device__ __forceinline__ u16 f2bf(float f) {   // round-to-nearest-even
    unsigned b = __float_as_uint(f);
    return (u16)((b + 0x7FFFu + ((b >> 16) & 1u)) >> 16);
}
__device__ __forceinline__ short8 ld8f(const float* p) {  // 8 fp32 -> 8 bf16
    const float4 v0 = *reinterpret_cast<const float4*>(p);
    const float4 v1 = *reinterpret_cast<const float4*>(p + 4);
    short8 r;
    r[0] = (short)f2bf(v0.x); r[1] = (short)f2bf(v0.y);
    r[2] = (short)f2bf(v0.z); r[3] = (short)f2bf(v0.w);
    r[4] = (short)f2bf(v1.x); r[5] = (short)f2bf(v1.y);
    r[6] = (short)f2bf(v1.z); r[7] = (short)f2bf(v1.w);
    return r;
}

// ---------------- W -> fragment-major bf16: Wt[(kb*256+c)*8+i] = W[kb*8+i][c]
__global__ __launch_bounds__(256)
void wt_kernel(const float* __restrict__ W, u16* __restrict__ Wt)
{
    const int id = blockIdx.x * 256 + threadIdx.x;
    const int kb = id >> 8, c = id & 255;
    #pragma unroll
    for (int i = 0; i < 8; ++i)
        Wt[((size_t)kb * 256 + c) * 8 + i] = f2bf(W[(size_t)(kb * 8 + i) * 256 + c]);
}

// ---------------- MFMA GEMM: C[M x 256] = epilogue(A[M x K] @ W[K x 256]) ---
// 256 thr = 4 waves; block = 64 rows x 256 cols; wave w owns cols [w*64,w*64+64).
// A-tile staged ONCE in LDS as bf16 (coalesced full-row gathers, fused
// subtract for MODE 1), stride KTOT+8 u16 -> uniform bank load on
// ds_read_b128 (row offset = 4 words mod 32). W fragments direct from L2
// (fragment-major). One __syncthreads; no K-loop barriers.
// Operand-swapped 16x16x32 bf16 MFMA: lane l -> row r0+g*16+(l&15),
// cols w*64 + t*16 + (l>>4)*4 + v.
// MODE 0: A = [x[src[e]] | ea[e]]           -> h0 = relu(acc)          K=192
// MODE 1: A = ns[src[e]] - hp[rev[e]]       -> h = relu(h0 + acc)      K=256
// MODE 2: A = [x[n] | ns[n]]                -> out[batch]+=relu(acc+b3) K=384
template<int MODE, int KTOT>
__global__ __launch_bounds__(256, 4)
void mfma_gemm(const float* __restrict__ x,
               const float* __restrict__ ea,
               const u16*   __restrict__ ns,
               const u16*   __restrict__ hp,
               const u16*   __restrict__ h0,
               const int*   __restrict__ src,
               const int*   __restrict__ rev,
               const int*   __restrict__ batch,
               const u16*   __restrict__ Wt,
               const float* __restrict__ b3,
               void*        __restrict__ outv)
{
    constexpr int CH  = KTOT / 8;        // 16B chunks per row
    constexpr int S   = KTOT + 8;        // padded LDS stride (u16)
    constexpr int NIT = 64 * CH / 256;   // staging iterations (6/8/12)

    __shared__ __align__(16) u16 As[64 * S];

    const int tid = threadIdx.x;
    const int l   = tid & 63;
    const int w   = tid >> 6;
    const int q   = l >> 4;
    const int rl  = l & 15;
    const int r0  = blockIdx.x * 64;

    // ---- stage A-tile: full-row coalesced gathers, bf16, fused subtract
    #pragma unroll
    for (int it = 0; it < NIT; ++it) {
        const int idx = it * 256 + tid;
        const int row = idx / CH;
        const int c0  = (idx - row * CH) * 8;
        const int gr  = r0 + row;
        short8 v;
        if (MODE == 0) {
            v = (c0 < XDIM) ? ld8f(x  + (size_t)src[gr] * XDIM + c0)
                            : ld8f(ea + (size_t)gr * EDIM + (c0 - XDIM));
        } else if (MODE == 1) {
            const short8 a = *reinterpret_cast<const short8*>(ns + (size_t)src[gr] * HID + c0);
            const short8 b = *reinterpret_cast<const short8*>(hp + (size_t)rev[gr] * HID + c0);
            #pragma unroll
            for (int i = 0; i < 8; ++i)
                v[i] = (short)f2bf(bf2f((u16)a[i]) - bf2f((u16)b[i]));
        } else {
            if (c0 < XDIM) v = ld8f(x + (size_t)gr * XDIM + c0);
            else v = *reinterpret_cast<const short8*>(ns + (size_t)gr * HID + (c0 - XDIM));
        }
        *reinterpret_cast<short8*>(&As[row * S + c0]) = v;
    }
    __syncthreads();

    // ---- K loop: W frags from L2, A frags from LDS
    const u16* Wb = Wt + ((size_t)q * 256 + w * 64 + rl) * 8;

    f32x4 acc[4][4];
    #pragma unroll
    for (int g = 0; g < 4; ++g)
        #pragma unroll
        for (int t = 0; t < 4; ++t)
            acc[g][t] = (f32x4){0.f, 0.f, 0.f, 0.f};

    for (int kk = 0; kk < KTOT; kk += 32) {
        short8 bfr[4];
        #pragma unroll
        for (int t = 0; t < 4; ++t)   // (kk/8)*2048 == kk*256 (u16 elements)
            bfr[t] = *reinterpret_cast<const short8*>(Wb + (size_t)kk * 256 + t * 128);

        short8 afr[4];
        #pragma unroll
        for (int g = 0; g < 4; ++g)
            afr[g] = *reinterpret_cast<const short8*>(&As[(g * 16 + rl) * S + q * 8 + kk]);

        #pragma unroll
        for (int g = 0; g < 4; ++g)
            #pragma unroll
            for (int t = 0; t < 4; ++t)
                acc[g][t] = __builtin_amdgcn_mfma_f32_16x16x32_bf16(
                                bfr[t], afr[g], acc[g][t], 0, 0, 0);
    }

    // ---- epilogue: lane l holds C[r0+g*16+rl][w*64 + t*16 + q*4 + v]
    #pragma unroll
    for (int g = 0; g < 4; ++g) {
        const int row = r0 + g * 16 + rl;
        if (MODE == 2) {
            const int gb = batch[row];
            float* op = (float*)outv + (size_t)gb * HID;
            #pragma unroll
            for (int t = 0; t < 4; ++t) {
                const int c0 = w * 64 + t * 16 + q * 4;
                #pragma unroll
                for (int v = 0; v < 4; ++v) {
                    const float r = fmaxf(acc[g][t][v] + b3[c0 + v], 0.f);
                    atomicAdd(op + c0 + v, r);
                }
            }
        } else {
            u16* op = (u16*)outv + (size_t)row * HID;
            #pragma unroll
            for (int t = 0; t < 4; ++t) {
                const int c0 = w * 64 + t * 16 + q * 4;
                float e0 = acc[g][t][0], e1 = acc[g][t][1];
                float e2 = acc[g][t][2], e3 = acc[g][t][3];
                if (MODE == 1) {
                    const ushort4 hv = *reinterpret_cast<const ushort4*>(
                        h0 + (size_t)row * HID + c0);
                    e0 += bf2f(hv.x); e1 += bf2f(hv.y);
                    e2 += bf2f(hv.z); e3 += bf2f(hv.w);
                }
                ushort4 o;
                o.x = f2bf(fmaxf(e0, 0.f)); o.y = f2bf(fmaxf(e1, 0.f));
                o.z = f2bf(fmaxf(e2, 0.f)); o.w = f2bf(fmaxf(e3, 0.f));
                *reinterpret_cast<ushort4*>(op + c0) = o;
            }
        }
    }
}

// ---------------- CSR build (dst fixed per launch) --------------------------
__global__ __launch_bounds__(256)
void hist_kernel(const int* __restrict__ dst, int* __restrict__ deg)
{
    const int e = blockIdx.x * 256 + threadIdx.x;
    atomicAdd(&deg[dst[e]], 1);
}

__global__ __launch_bounds__(256)
void scan1_kernel(int* __restrict__ off, int* __restrict__ part)
{
    __shared__ int buf[256];
    const int t = threadIdx.x;
    const int i = blockIdx.x * 256 + t;
    const int v = off[i];
    buf[t] = v; __syncthreads();
    #pragma unroll
    for (int o = 1; o < 256; o <<= 1) {
        const int val = (t >= o) ? buf[t - o] : 0;
        __syncthreads();
        buf[t] += val;
        __syncthreads();
    }
    off[i] = buf[t] - v;
    if (t == 255) part[blockIdx.x] = buf[t];
}

__global__ __launch_bounds__(1024)
void scan2_kernel(int* __restrict__ part)
{
    __shared__ int buf[1024];
    const int t = threadIdx.x;
    const int v = (t < SCAN_B) ? part[t] : 0;
    buf[t] = v; __syncthreads();
    #pragma unroll
    for (int o = 1; o < 1024; o <<= 1) {
        const int val = (t >= o) ? buf[t - o] : 0;
        __syncthreads();
        buf[t] += val;
        __syncthreads();
    }
    if (t < SCAN_B) part[t] = buf[t] - v;
}

__global__ __launch_bounds__(256)
void scan3_kernel(int* __restrict__ off, const int* __restrict__ part,
                  int* __restrict__ pos)
{
    const int i = blockIdx.x * 256 + threadIdx.x;
    const int v = off[i] + part[blockIdx.x];
    off[i] = v;
    pos[i] = v;
    if (i == 0) off[N_NODES_C] = E_EDGES;
}

__global__ __launch_bounds__(256)
void fill_kernel(const int* __restrict__ dst, int* __restrict__ pos,
                 int* __restrict__ elist)
{
    const int e = blockIdx.x * 256 + threadIdx.x;
    const int idx = atomicAdd(&pos[dst[e]], 1);
    elist[idx] = e;
}

// ---------------- segment_sum via CSR gather (bf16) -------------------------
__global__ __launch_bounds__(256)
void gather_bf(const u16* __restrict__ h, const int* __restrict__ off,
               const int* __restrict__ elist, u16* __restrict__ ns)
{
    const size_t gid = (size_t)blockIdx.x * 256 + threadIdx.x;
    const int n = (int)(gid >> 6);
    const int c = (int)(gid & 63) * 4;
    const int s = off[n], e1 = off[n + 1];
    float a0 = 0.f, a1 = 0.f, a2 = 0.f, a3 = 0.f;
    for (int p = s; p < e1; ++p) {
        const int e = elist[p];
        const ushort4 v = *reinterpret_cast<const ushort4*>(h + (size_t)e * HID + c);
        a0 += bf2f(v.x); a1 += bf2f(v.y); a2 += bf2f(v.z); a3 += bf2f(v.w);
    }
    ushort4 o;
    o.x = f2bf(a0); o.y = f2bf(a1); o.z = f2bf(a2); o.w = f2bf(a3);
    *reinterpret_cast<ushort4*>(ns + (size_t)n * HID + c) = o;
}

extern "C" void kernel_launch(void* const* d_in, const int* in_sizes, int n_in,
                              void* d_out, int out_size, void* d_ws, size_t ws_size,
                              hipStream_t stream)
{
    const float* x     = (const float*)d_in[0];
    const int*   eidx  = (const int*)  d_in[1];
    const int*   rev   = (const int*)  d_in[2];
    const float* ea    = (const float*)d_in[3];
    const int*   batch = (const int*)  d_in[5];
    const float* W1    = (const float*)d_in[6];
    const float* W2    = (const float*)d_in[7];
    const float* W3    = (const float*)d_in[8];
    const float* b3    = (const float*)d_in[9];
    float*       out   = (float*)d_out;

    const int* src = eidx;
    const int* dst = eidx + E_EDGES;

    char* base = (ws_size >= WS_NEED) ? (char*)d_ws : (char*)g_fb;
    u16* h0  = (u16*)(base);
    u16* hB  = (u16*)(base + SZ_HB);
    u16* hC  = (u16*)(base + 2 * SZ_HB);
    u16* ns  = (u16*)(base + 3 * SZ_HB);
    u16* wt1 = (u16*)(base + 3 * SZ_HB + SZ_NSB);
    u16* wt2 = wt1 + (size_t)24 * 256 * 8;   // K=192 -> 24 kb
    u16* wt3 = wt2 + (size_t)32 * 256 * 8;   // K=256 -> 32 kb
    int* off   = (int*)(base + 3 * SZ_HB + SZ_NSB + SZ_WT);
    int* pos   = off + (N_NODES_C + 1);
    int* elist = pos + N_NODES_C;
    int* part  = elist + E_EDGES;

    const dim3 blk(256);
    const int gE  = E_EDGES / 64;     // 10000
    const int gN  = N_NODES_C / 64;   // 2500
    const int gEt = E_EDGES / 256;    // 2500
    const int gNg = N_NODES_C / 4;    // 40000: 1 wave per node

    // weights -> fragment-major bf16
    wt_kernel<<<24, blk, 0, stream>>>(W1, wt1);
    wt_kernel<<<32, blk, 0, stream>>>(W2, wt2);
    wt_kernel<<<48, blk, 0, stream>>>(W3, wt3);

    // CSR over dst (reused by all 3 segment-sums)
    hipMemsetAsync(off, 0, (N_NODES_C + 1) * sizeof(int), stream);
    hist_kernel <<<gEt,    blk, 0, stream>>>(dst, off);
    scan1_kernel<<<SCAN_B, blk, 0, stream>>>(off, part);
    scan2_kernel<<<1,     1024, 0, stream>>>(part);
    scan3_kernel<<<SCAN_B, blk, 0, stream>>>(off, part, pos);
    fill_kernel <<<gEt,    blk, 0, stream>>>(dst, pos, elist);

    // h0 = relu([x[src]|ea] @ W1)
    mfma_gemm<0, 192><<<gE, blk, 0, stream>>>(x, ea, nullptr, nullptr, nullptr,
                                              src, nullptr, nullptr, wt1, nullptr, h0);
    // iter 1
    gather_bf<<<gNg, blk, 0, stream>>>(h0, off, elist, ns);
    mfma_gemm<1, 256><<<gE, blk, 0, stream>>>(nullptr, nullptr, ns, h0, h0,
                                              src, rev, nullptr, wt2, nullptr, hB);
    // iter 2
    gather_bf<<<gNg, blk, 0, stream>>>(hB, off, elist, ns);
    mfma_gemm<1, 256><<<gE, blk, 0, stream>>>(nullptr, nullptr, ns, hB, h0,
                                              src, rev, nullptr, wt2, nullptr, hC);
    // v_msg
    gather_bf<<<gNg, blk, 0, stream>>>(hC, off, elist, ns);
    // out[g] += relu([x|ns] @ W3 + b3)
    hipMemsetAsync(out, 0, (size_t)out_size * sizeof(float), stream);
    mfma_gemm<2, 384><<<gN, blk, 0, stream>>>(x, nullptr, ns, nullptr, nullptr,
                                              nullptr, nullptr, batch, wt3, b3, out);
}

// Round 8
// 1798.974 us; speedup vs baseline: 6.0409x; 2.0242x over previous
//
#include <hip/hip_runtime.h>
#include <hip/hip_bf16.h>
#include <cstdint>
#include <cstddef>

#define E_EDGES   640000
#define N_NODES_C 160000
#define N_GRAPHS  5000
#define HID       256
#define XDIM      128
#define EDIM      64
#define SCAN_B    625            // N_NODES_C / 256

typedef unsigned short u16;
typedef __attribute__((ext_vector_type(8))) short short8;  // 8 bf16 = 4 VGPR
typedef __attribute__((ext_vector_type(4))) float f32x4;   // MFMA C/D

static constexpr size_t SZ_HB  = (size_t)E_EDGES * HID * 2;       // 327,680,000
static constexpr size_t SZ_NSB = (size_t)N_NODES_C * HID * 2;     // 81,920,000
static constexpr size_t SZ_WT  = (size_t)((192 + 256 + 384) / 8) * HID * 8 * 2;
static constexpr size_t SZ_CSR = (size_t)(2 * N_NODES_C + 1 + E_EDGES + 8192) * 4;
static constexpr size_t WS_NEED = 3 * SZ_HB + SZ_NSB + SZ_WT + SZ_CSR; // ~1.07 GB

static void* g_fb = nullptr;
__attribute__((constructor))
static void _fb_alloc() { (void)hipMalloc(&g_fb, WS_NEED); }

__device__ __forceinline__ float bf2f(u16 u) {
    return __uint_as_float(((unsigned)u) << 16);
}
__device__ __forceinline__ u16 f2bf(float f) {   // round-to-nearest-even
    unsigned b = __float_as_uint(f);
    return (u16)((b + 0x7FFFu + ((b >> 16) & 1u)) >> 16);
}
__device__ __forceinline__ short8 ld8f(const float* p) {  // 8 fp32 -> 8 bf16
    const float4 v0 = *reinterpret_cast<const float4*>(p);
    const float4 v1 = *reinterpret_cast<const float4*>(p + 4);
    short8 r;
    r[0] = (short)f2bf(v0.x); r[1] = (short)f2bf(v0.y);
    r[2] = (short)f2bf(v0.z); r[3] = (short)f2bf(v0.w);
    r[4] = (short)f2bf(v1.x); r[5] = (short)f2bf(v1.y);
    r[6] = (short)f2bf(v1.z); r[7] = (short)f2bf(v1.w);
    return r;
}

// ---------------- W -> fragment-major bf16: Wt[(kb*256+c)*8+i] = W[kb*8+i][c]
__global__ __launch_bounds__(256)
void wt_kernel(const float* __restrict__ W, u16* __restrict__ Wt)
{
    const int id = blockIdx.x * 256 + threadIdx.x;
    const int kb = id >> 8, c = id & 255;
    #pragma unroll
    for (int i = 0; i < 8; ++i)
        Wt[((size_t)kb * 256 + c) * 8 + i] = f2bf(W[(size_t)(kb * 8 + i) * 256 + c]);
}

// ---------------- MFMA GEMM: C[M x 256] = epilogue(A[M x K] @ W[K x 256]) ---
// 256 thr = 4 waves; block = 64 rows x 256 cols; wave w owns cols [w*64,w*64+64).
// A-tile staged ONCE in LDS (coalesced full-row gathers, fused subtract in
// MODE 1), stride KTOT+8 u16. W fragments direct from L2 (fragment-major).
// One __syncthreads. Operand-swapped 16x16x32 bf16 MFMA: lane l -> row
// r0+g*16+(l&15), cols w*64 + t*16 + (l>>4)*4 + v.
// MODE 0: A = [x[src[e]] | ea[e]]     -> h0 = relu(acc)                K=192
// MODE 1: A = ns[src[e]] - hp[rev[e]] -> h = relu(h0 + acc)            K=256
// MODE 2: A = [x[n] | ns[n]]          -> na = relu(acc + b3)  (bf16)   K=384
template<int MODE, int KTOT>
__global__ __launch_bounds__(256, 4)
void mfma_gemm(const float* __restrict__ x,
               const float* __restrict__ ea,
               const u16*   __restrict__ ns,
               const u16*   __restrict__ hp,
               const u16*   __restrict__ h0,
               const int*   __restrict__ src,
               const int*   __restrict__ rev,
               const u16*   __restrict__ Wt,
               const float* __restrict__ b3,
               u16*         __restrict__ out)
{
    constexpr int CH  = KTOT / 8;        // 16B chunks per row
    constexpr int S   = KTOT + 8;        // padded LDS stride (u16)
    constexpr int NIT = 64 * CH / 256;   // staging iterations (6/8/12)

    __shared__ __align__(16) u16 As[64 * S];

    const int tid = threadIdx.x;
    const int l   = tid & 63;
    const int w   = tid >> 6;
    const int q   = l >> 4;
    const int rl  = l & 15;
    const int r0  = blockIdx.x * 64;

    // ---- stage A-tile: full-row coalesced gathers, bf16, fused subtract
    #pragma unroll
    for (int it = 0; it < NIT; ++it) {
        const int idx = it * 256 + tid;
        const int row = idx / CH;
        const int c0  = (idx - row * CH) * 8;
        const int gr  = r0 + row;
        short8 v;
        if (MODE == 0) {
            v = (c0 < XDIM) ? ld8f(x  + (size_t)src[gr] * XDIM + c0)
                            : ld8f(ea + (size_t)gr * EDIM + (c0 - XDIM));
        } else if (MODE == 1) {
            const short8 a = *reinterpret_cast<const short8*>(ns + (size_t)src[gr] * HID + c0);
            const short8 b = *reinterpret_cast<const short8*>(hp + (size_t)rev[gr] * HID + c0);
            #pragma unroll
            for (int i = 0; i < 8; ++i)
                v[i] = (short)f2bf(bf2f((u16)a[i]) - bf2f((u16)b[i]));
        } else {
            if (c0 < XDIM) v = ld8f(x + (size_t)gr * XDIM + c0);
            else v = *reinterpret_cast<const short8*>(ns + (size_t)gr * HID + (c0 - XDIM));
        }
        *reinterpret_cast<short8*>(&As[row * S + c0]) = v;
    }
    __syncthreads();

    // ---- K loop: W frags from L2, A frags from LDS
    const u16* Wb = Wt + ((size_t)q * 256 + w * 64 + rl) * 8;

    f32x4 acc[4][4];
    #pragma unroll
    for (int g = 0; g < 4; ++g)
        #pragma unroll
        for (int t = 0; t < 4; ++t)
            acc[g][t] = (f32x4){0.f, 0.f, 0.f, 0.f};

    for (int kk = 0; kk < KTOT; kk += 32) {
        short8 bfr[4];
        #pragma unroll
        for (int t = 0; t < 4; ++t)   // (kk/8)*2048 == kk*256 (u16 elements)
            bfr[t] = *reinterpret_cast<const short8*>(Wb + (size_t)kk * 256 + t * 128);

        short8 afr[4];
        #pragma unroll
        for (int g = 0; g < 4; ++g)
            afr[g] = *reinterpret_cast<const short8*>(&As[(g * 16 + rl) * S + q * 8 + kk]);

        #pragma unroll
        for (int g = 0; g < 4; ++g)
            #pragma unroll
            for (int t = 0; t < 4; ++t)
                acc[g][t] = __builtin_amdgcn_mfma_f32_16x16x32_bf16(
                                bfr[t], afr[g], acc[g][t], 0, 0, 0);
    }

    // ---- epilogue: lane l holds C[r0+g*16+rl][w*64 + t*16 + q*4 + v]
    #pragma unroll
    for (int g = 0; g < 4; ++g) {
        const int row = r0 + g * 16 + rl;
        u16* op = out + (size_t)row * HID;
        #pragma unroll
        for (int t = 0; t < 4; ++t) {
            const int c0 = w * 64 + t * 16 + q * 4;
            float e0 = acc[g][t][0], e1 = acc[g][t][1];
            float e2 = acc[g][t][2], e3 = acc[g][t][3];
            if (MODE == 1) {
                const ushort4 hv = *reinterpret_cast<const ushort4*>(
                    h0 + (size_t)row * HID + c0);
                e0 += bf2f(hv.x); e1 += bf2f(hv.y);
                e2 += bf2f(hv.z); e3 += bf2f(hv.w);
            } else if (MODE == 2) {
                e0 += b3[c0 + 0]; e1 += b3[c0 + 1];
                e2 += b3[c0 + 2]; e3 += b3[c0 + 3];
            }
            ushort4 o;
            o.x = f2bf(fmaxf(e0, 0.f)); o.y = f2bf(fmaxf(e1, 0.f));
            o.z = f2bf(fmaxf(e2, 0.f)); o.w = f2bf(fmaxf(e3, 0.f));
            *reinterpret_cast<ushort4*>(op + c0) = o;
        }
    }
}

// ---------------- CSR build (dst fixed per launch) --------------------------
__global__ __launch_bounds__(256)
void hist_kernel(const int* __restrict__ dst, int* __restrict__ deg)
{
    const int e = blockIdx.x * 256 + threadIdx.x;
    atomicAdd(&deg[dst[e]], 1);
}

__global__ __launch_bounds__(256)
void scan1_kernel(int* __restrict__ off, int* __restrict__ part)
{
    __shared__ int buf[256];
    const int t = threadIdx.x;
    const int i = blockIdx.x * 256 + t;
    const int v = off[i];
    buf[t] = v; __syncthreads();
    #pragma unroll
    for (int o = 1; o < 256; o <<= 1) {
        const int val = (t >= o) ? buf[t - o] : 0;
        __syncthreads();
        buf[t] += val;
        __syncthreads();
    }
    off[i] = buf[t] - v;
    if (t == 255) part[blockIdx.x] = buf[t];
}

__global__ __launch_bounds__(1024)
void scan2_kernel(int* __restrict__ part)
{
    __shared__ int buf[1024];
    const int t = threadIdx.x;
    const int v = (t < SCAN_B) ? part[t] : 0;
    buf[t] = v; __syncthreads();
    #pragma unroll
    for (int o = 1; o < 1024; o <<= 1) {
        const int val = (t >= o) ? buf[t - o] : 0;
        __syncthreads();
        buf[t] += val;
        __syncthreads();
    }
    if (t < SCAN_B) part[t] = buf[t] - v;
}

__global__ __launch_bounds__(256)
void scan3_kernel(int* __restrict__ off, const int* __restrict__ part,
                  int* __restrict__ pos)
{
    const int i = blockIdx.x * 256 + threadIdx.x;
    const int v = off[i] + part[blockIdx.x];
    off[i] = v;
    pos[i] = v;
    if (i == 0) off[N_NODES_C] = E_EDGES;
}

__global__ __launch_bounds__(256)
void fill_kernel(const int* __restrict__ dst, int* __restrict__ pos,
                 int* __restrict__ elist)
{
    const int e = blockIdx.x * 256 + threadIdx.x;
    const int idx = atomicAdd(&pos[dst[e]], 1);
    elist[idx] = e;
}

// ---------------- graph offsets from sorted batch ---------------------------
__global__ __launch_bounds__(256)
void goff_kernel(const int* __restrict__ batch, int* __restrict__ goff)
{
    const int i = blockIdx.x * 256 + threadIdx.x;
    const int b = batch[i];
    const int prev = (i == 0) ? -1 : batch[i - 1];
    for (int g = prev + 1; g <= b; ++g) goff[g] = i;          // handles empties
    if (i == N_NODES_C - 1)
        for (int g = b + 1; g <= N_GRAPHS; ++g) goff[g] = N_NODES_C;
}

// ---------------- segment_sum via CSR gather (bf16) -------------------------
__global__ __launch_bounds__(256)
void gather_bf(const u16* __restrict__ h, const int* __restrict__ off,
               const int* __restrict__ elist, u16* __restrict__ ns)
{
    const size_t gid = (size_t)blockIdx.x * 256 + threadIdx.x;
    const int n = (int)(gid >> 6);
    const int c = (int)(gid & 63) * 4;
    const int s = off[n], e1 = off[n + 1];
    float a0 = 0.f, a1 = 0.f, a2 = 0.f, a3 = 0.f;
    for (int p = s; p < e1; ++p) {
        const int e = elist[p];
        const ushort4 v = *reinterpret_cast<const ushort4*>(h + (size_t)e * HID + c);
        a0 += bf2f(v.x); a1 += bf2f(v.y); a2 += bf2f(v.z); a3 += bf2f(v.w);
    }
    ushort4 o;
    o.x = f2bf(a0); o.y = f2bf(a1); o.z = f2bf(a2); o.w = f2bf(a3);
    *reinterpret_cast<ushort4*>(ns + (size_t)n * HID + c) = o;
}

// ---------------- global add pool over contiguous graph ranges --------------
// One wave per graph: 64 lanes x 4 cols. fp32 accumulate, direct store.
__global__ __launch_bounds__(256)
void pool_kernel(const u16* __restrict__ na, const int* __restrict__ goff,
                 float* __restrict__ out)
{
    const size_t gid = (size_t)blockIdx.x * 256 + threadIdx.x;
    const int g = (int)(gid >> 6);
    const int c = (int)(gid & 63) * 4;
    const int s = goff[g], e1 = goff[g + 1];
    float a0 = 0.f, a1 = 0.f, a2 = 0.f, a3 = 0.f;
    for (int r = s; r < e1; ++r) {
        const ushort4 v = *reinterpret_cast<const ushort4*>(na + (size_t)r * HID + c);
        a0 += bf2f(v.x); a1 += bf2f(v.y); a2 += bf2f(v.z); a3 += bf2f(v.w);
    }
    *reinterpret_cast<float4*>(out + (size_t)g * HID + c) =
        make_float4(a0, a1, a2, a3);
}

extern "C" void kernel_launch(void* const* d_in, const int* in_sizes, int n_in,
                              void* d_out, int out_size, void* d_ws, size_t ws_size,
                              hipStream_t stream)
{
    const float* x     = (const float*)d_in[0];
    const int*   eidx  = (const int*)  d_in[1];
    const int*   rev   = (const int*)  d_in[2];
    const float* ea    = (const float*)d_in[3];
    const int*   batch = (const int*)  d_in[5];
    const float* W1    = (const float*)d_in[6];
    const float* W2    = (const float*)d_in[7];
    const float* W3    = (const float*)d_in[8];
    const float* b3    = (const float*)d_in[9];
    float*       out   = (float*)d_out;

    const int* src = eidx;
    const int* dst = eidx + E_EDGES;

    char* base = (ws_size >= WS_NEED) ? (char*)d_ws : (char*)g_fb;
    u16* h0  = (u16*)(base);
    u16* hB  = (u16*)(base + SZ_HB);
    u16* hC  = (u16*)(base + 2 * SZ_HB);
    u16* ns  = (u16*)(base + 3 * SZ_HB);
    u16* na  = h0;                            // h0 buffer is free after iter 2
    u16* wt1 = (u16*)(base + 3 * SZ_HB + SZ_NSB);
    u16* wt2 = wt1 + (size_t)24 * 256 * 8;    // K=192 -> 24 kb
    u16* wt3 = wt2 + (size_t)32 * 256 * 8;    // K=256 -> 32 kb
    int* off   = (int*)(base + 3 * SZ_HB + SZ_NSB + SZ_WT);
    int* pos   = off + (N_NODES_C + 1);
    int* elist = pos + N_NODES_C;
    int* part  = elist + E_EDGES;
    int* goff  = part + 1024;                 // 5001 ints

    const dim3 blk(256);
    const int gE  = E_EDGES / 64;     // 10000
    const int gN  = N_NODES_C / 64;   // 2500
    const int gEt = E_EDGES / 256;    // 2500
    const int gNg = N_NODES_C / 4;    // 40000: 1 wave per node
    const int gPg = N_GRAPHS / 4;     // 1250:  1 wave per graph

    // weights -> fragment-major bf16
    wt_kernel<<<24, blk, 0, stream>>>(W1, wt1);
    wt_kernel<<<32, blk, 0, stream>>>(W2, wt2);
    wt_kernel<<<48, blk, 0, stream>>>(W3, wt3);

    // CSR over dst (reused by all 3 segment-sums) + graph offsets
    hipMemsetAsync(off, 0, (N_NODES_C + 1) * sizeof(int), stream);
    hist_kernel <<<gEt,    blk, 0, stream>>>(dst, off);
    scan1_kernel<<<SCAN_B, blk, 0, stream>>>(off, part);
    scan2_kernel<<<1,     1024, 0, stream>>>(part);
    scan3_kernel<<<SCAN_B, blk, 0, stream>>>(off, part, pos);
    fill_kernel <<<gEt,    blk, 0, stream>>>(dst, pos, elist);
    goff_kernel <<<SCAN_B, blk, 0, stream>>>(batch, goff);

    // h0 = relu([x[src]|ea] @ W1)
    mfma_gemm<0, 192><<<gE, blk, 0, stream>>>(x, ea, nullptr, nullptr, nullptr,
                                              src, nullptr, wt1, nullptr, h0);
    // iter 1
    gather_bf<<<gNg, blk, 0, stream>>>(h0, off, elist, ns);
    mfma_gemm<1, 256><<<gE, blk, 0, stream>>>(nullptr, nullptr, ns, h0, h0,
                                              src, rev, wt2, nullptr, hB);
    // iter 2
    gather_bf<<<gNg, blk, 0, stream>>>(hB, off, elist, ns);
    mfma_gemm<1, 256><<<gE, blk, 0, stream>>>(nullptr, nullptr, ns, hB, h0,
                                              src, rev, wt2, nullptr, hC);
    // v_msg
    gather_bf<<<gNg, blk, 0, stream>>>(hC, off, elist, ns);
    // na = relu([x|ns] @ W3 + b3)   (bf16, into h0 buffer)
    mfma_gemm<2, 384><<<gN, blk, 0, stream>>>(x, nullptr, ns, nullptr, nullptr,
                                              nullptr, nullptr, wt3, b3, na);
    // out[g] = sum over contiguous node range (batch sorted), no atomics
    pool_kernel<<<gPg, blk, 0, stream>>>(na, goff, out);
}